// Round 13
// baseline (284.696 us; speedup 1.0000x reference)
//
#include <hip/hip_runtime.h>
#include <hip/hip_bf16.h>

using bf16 = __hip_bfloat16;

#define NA 50000
#define NE 600000

// 96 chunks x 12500 edges; hist rows padded to 100032 bins (3 passes x 33344)
#define NCH 96
#define CHE 12500
#define HROW 100032
#define PBINS 33344

typedef __attribute__((ext_vector_type(8))) short short8;
typedef __attribute__((ext_vector_type(4))) float f32x4;

// ---- ws layout (BYTE offsets). Total ~80.1 MB (< proven-safe 81.6 MB) ----
#define HBUF_B   0u            // bf16 50000x256                      25.6 MB
#define FS_B     25600000u     // bf16 2 x 50000x128                  25.6 MB
#define EL_B     51200000u     // f32 4 x 200,000: el_gt, er_gt, el_uav, er_uav
#define RECS_B   54400000u     // 12B recs x 1.2M {src,ee01,ee23}     14.4 MB
#define HIST_B   68800000u     // u8 [96][100032] counts -> prefixes   9.6 MB
#define ROW_B    78403072u     // u32 100001 LOCAL row offsets (block-local)
#define TOPS_B   78803076u     // u32 128: [0..97] block bases, [120] ticket
#define FLAG_B   78803588u     // int dtype flag
#define WST_GT_B 78803600u     // bf16 128x64 transposed W_src_gt     16 KB
#define WST_UAV_B 78819984u    // bf16 128x64                         16 KB
#define WRT_B    78836368u     // bf16 256x64 transposed [Wres_gt|Wres_uav]
#define WFT_B    78869136u     // bf16 128x256 transposed W_f         64 KB
#define ELT_GT_B 78934672u     // bf16 16x64 el-weights gt (rows 4-15 zero)
#define ELT_UAV_B 78936720u    // bf16 16x64
#define ERT_B    78938768u     // bf16 16x64 er gt rows0-3, uav rows4-7, 8-15 zero
#define RANK8_B  78940816u     // u8 1.2M per-edge local rank (captured in fused_k)
#define WS_BYTES 80140816u

__device__ __forceinline__ float b2f(bf16 v) { return __bfloat162float(v); }

__device__ __forceinline__ float ldf(const void* p, size_t i, int f32) {
    return f32 ? ((const float*)p)[i] : b2f(((const bf16*)p)[i]);
}

__device__ __forceinline__ unsigned short f2bs(float v) {
    bf16 t = __float2bfloat16(v);
    return *(unsigned short*)&t;
}

__device__ __forceinline__ float lrelu_exp(float v) {
    v = v > 0.f ? v : 0.2f * v;
    return __expf(v);
}

__device__ __forceinline__ unsigned int pack_bf16x2(float a, float b) {
    return (unsigned int)f2bs(a) | ((unsigned int)f2bs(b) << 16);
}

__device__ __forceinline__ float lo_f(unsigned int u) { return __uint_as_float(u << 16); }
__device__ __forceinline__ float hi_f(unsigned int u) { return __uint_as_float(u & 0xffff0000u); }

// v_dot2_f32_bf16 (VOP3P, CDNA3+): d = a.bf16[0]*b.bf16[0] + a.bf16[1]*b.bf16[1] + c
__device__ __forceinline__ float dot2bf(unsigned int a, unsigned int b, float c) {
    float d;
    asm("v_dot2_f32_bf16 %0, %1, %2, %3" : "=v"(d) : "v"(a), "v"(b), "v"(c));
    return d;
}

__device__ __forceinline__ short8 ldfrag8(const void* p, size_t off, int f32) {
    if (!f32) return *(const short8*)((const unsigned short*)p + off);
    union { short8 s; unsigned int u[4]; } r;
    const float* fp = (const float*)p + off;
#pragma unroll
    for (int j = 0; j < 4; ++j) r.u[j] = pack_bf16x2(fp[2 * j], fp[2 * j + 1]);
    return r.s;
}

__device__ int probe_f32(const void* x0) {
    __shared__ int cnt;
    if (threadIdx.x == 0) cnt = 0;
    __syncthreads();
    const bf16* p = (const bf16*)x0;
    int bad = 0;
    for (int i = threadIdx.x; i < 1024; i += 256) {
        float av = fabsf(b2f(p[i]));
        if (!(av <= 1e6f)) bad++;
    }
    if (bad) atomicAdd(&cnt, bad);
    __syncthreads();
    return cnt > 8;
}

// prep (weights only): 21 blocks convert weight tables + set flag/sentinel.
// Transposes READ COALESCED, scatter-write the transposed table.
__global__ void HeteroVisionConv_29703993819529_kernel(
    const void* x0,
    const void* Wsg, const void* alg, const void* Wdg, const void* arg_,
    const void* Wsu, const void* alu, const void* Wdu, const void* aru,
    const void* Wrg, const void* Wru, const void* Wf,
    unsigned short* wsT_gt, unsigned short* wsT_uav, unsigned short* wrT,
    unsigned short* wfT, unsigned short* elT_gt, unsigned short* elT_uav,
    unsigned short* erT, unsigned int* tops,
    int* flag, unsigned int* outp, long sent) {
    int b = blockIdx.x, t = threadIdx.x;
    int f32 = probe_f32(x0);
    if (b == 20) {
        if (t == 0) { flag[0] = f32; tops[120] = 0u; outp[sent] = 0x447A447Au; }
        return;
    }
    if (b < 8) {               // WfT: source rows k in [b*32, b*32+32); Wf is 256x128
        for (int i = t; i < 32 * 128; i += 256) {
            int k = b * 32 + (i >> 7), n = i & 127;
            wfT[n * 256 + k] = f2bs(ldf(Wf, (size_t)k * 128 + n, f32));
        }
    } else if (b < 12) {       // WrT: source rows k in [(b-8)*16, +16); Wr* are 64x128
        for (int i = t; i < 16 * 256; i += 256) {
            int k = (b - 8) * 16 + (i >> 8), n = i & 255;
            float v = (n < 128) ? ldf(Wrg, (size_t)k * 128 + n, f32)
                                : ldf(Wru, (size_t)k * 128 + (n - 128), f32);
            wrT[n * 64 + k] = f2bs(v);
        }
    } else if (b < 14) {       // WsT_gt: source rows k in [(b-12)*32, +32); Wsg 64x128
        for (int i = t; i < 32 * 128; i += 256) {
            int k = (b - 12) * 32 + (i >> 7), n = i & 127;
            wsT_gt[n * 64 + k] = f2bs(ldf(Wsg, (size_t)k * 128 + n, f32));
        }
    } else if (b < 16) {       // WsT_uav halves
        for (int i = t; i < 32 * 128; i += 256) {
            int k = (b - 14) * 32 + (i >> 7), n = i & 127;
            wsT_uav[n * 64 + k] = f2bs(ldf(Wsu, (size_t)k * 128 + n, f32));
        }
    } else {                   // fold attn weights, m = b-16
        int m = b - 16;
        const void* Wm = (m == 0) ? Wsg : (m == 1) ? Wdg : (m == 2) ? Wsu : Wdu;
        const void* Am = (m == 0) ? alg : (m == 1) ? arg_ : (m == 2) ? alu : aru;
        int k = t >> 2, h = t & 3;
        float a = 0.f;
        for (int d = 0; d < 32; ++d)
            a += ldf(Wm, (size_t)k * 128 + h * 32 + d, f32) *
                 ldf(Am, (size_t)h * 32 + d, f32);
        unsigned short v = f2bs(a);
        if (m == 0) {
            elT_gt[h * 64 + k] = v;
            for (int i = t; i < 12 * 64; i += 256) elT_gt[(4 + (i >> 6)) * 64 + (i & 63)] = 0;
        } else if (m == 2) {
            elT_uav[h * 64 + k] = v;
            for (int i = t; i < 12 * 64; i += 256) elT_uav[(4 + (i >> 6)) * 64 + (i & 63)] = 0;
        } else if (m == 1) {
            erT[h * 64 + k] = v;
        } else {
            erT[(4 + h) * 64 + k] = v;
            for (int i = t; i < 8 * 64; i += 256) erT[(8 + (i >> 6)) * 64 + (i & 63)] = 0;
        }
    }
}

// fused_k: ATOMIC-FREE histogram (96 per-chunk blocks, LDS u8 counts,
// 3 bin-passes of 33344 bins reusing the Bt LDS) + node_fs/res MFMA blocks.
// hist[c][bin] = count of chunk-c edges in bin; LDS atomicAdd return value
// is the edge's local rank -> rank8[]. Grid: 96 + 1564 + 782 = 2442 blocks.
__global__ void fused_k(const int* dg, const int* du,
                        unsigned char* hist, unsigned char* rank8,
                        const void* xg, const void* xu, const void* xa,
                        const unsigned short* wsT_gt, const unsigned short* wsT_uav,
                        const unsigned short* elT_gt, const unsigned short* elT_uav,
                        const unsigned short* wrT, const unsigned short* erT,
                        const void* bg, const void* bu,
                        float* elbase, bf16* fs, bf16* hbuf, const int* flag) {
    __shared__ unsigned short Bt[256 * 72];  // 36 KB (hist reuses as u32[8336])
    __shared__ float bl[256];
    int b = blockIdx.x, t = threadIdx.x;

    if (b < NCH) {
        // ---- per-chunk histogram + rank capture, LDS-only counting ----
        int c = b;
        int g = c >= 48;
        int eoff = (c - g * 48) * CHE;
        const int* dp = (g ? du : dg) + eoff;
        unsigned char* rk = rank8 + (size_t)g * NE + eoff;
        unsigned int* h32 = (unsigned int*)Bt;
        for (int p = 0; p < 3; ++p) {
            int binLo = p * PBINS;
            unsigned int* out = (unsigned int*)(hist + (size_t)c * HROW + binLo);
            bool live = (binLo + PBINS > g * NA) && (binLo < g * NA + NA);
            if (!live) {  // chunk's bins don't intersect this pass: write zeros
                for (int i = t; i < PBINS / 4; i += 256) out[i] = 0u;
                continue;
            }
            for (int i = t; i < PBINS / 4; i += 256) h32[i] = 0u;
            __syncthreads();
            for (int i = t; i < CHE / 4; i += 256) {
                int4 d4 = *(const int4*)(dp + i * 4);
                int dd[4] = {d4.x, d4.y, d4.z, d4.w};
#pragma unroll
                for (int k = 0; k < 4; ++k) {
                    int rel = g * NA + dd[k] - binLo;
                    if (rel >= 0 && rel < PBINS) {
                        unsigned int sh8 = 8u * (rel & 3);
                        unsigned int old = atomicAdd(&h32[rel >> 2], 1u << sh8);
                        rk[i * 4 + k] = (unsigned char)((old >> sh8) & 255u);
                    }
                }
            }
            __syncthreads();
            for (int i = t; i < PBINS / 4; i += 256) out[i] = h32[i];
            __syncthreads();
        }
        return;
    }
    int nidx = b - NCH;
    int f32 = *flag;
    int lane = t & 63, w = t >> 6;
    int m = lane & 15, quad = lane >> 4;

    if (nidx < 1564) {
        // ---- node_fs: fs = x_src @ W_src + fused el GEMV ----
        int g = nidx / 782, bb = nidx % 782;
        const void* A = g ? xu : xg;
        const unsigned short* WT = g ? wsT_uav : wsT_gt;
        const unsigned short* ET = g ? elT_uav : elT_gt;
        float* elout = elbase + (g ? 400000 : 0);
        bf16* out = fs + (size_t)g * NA * 128;
        for (int i = t * 8; i < 128 * 64; i += 256 * 8) {
            short8 v = *(const short8*)(WT + i);
            int n = i >> 6, k = i & 63;
            *(short8*)&Bt[n * 72 + k] = v;
        }
        __syncthreads();
        int row = bb * 64 + w * 16 + m;
        int rowc = row < NA ? row : NA - 1;
        short8 a0 = ldfrag8(A, (size_t)rowc * 64 + quad * 8, f32);
        short8 a1 = ldfrag8(A, (size_t)rowc * 64 + 32 + quad * 8, f32);
        f32x4 acc[8];
#pragma unroll
        for (int nt = 0; nt < 8; ++nt) acc[nt] = (f32x4){0.f, 0.f, 0.f, 0.f};
#pragma unroll
        for (int nt = 0; nt < 8; ++nt) {
            short8 b0 = *(const short8*)&Bt[(nt * 16 + m) * 72 + quad * 8];
            short8 b1 = *(const short8*)&Bt[(nt * 16 + m) * 72 + 32 + quad * 8];
            acc[nt] = __builtin_amdgcn_mfma_f32_16x16x32_bf16(a0, b0, acc[nt], 0, 0, 0);
            acc[nt] = __builtin_amdgcn_mfma_f32_16x16x32_bf16(a1, b1, acc[nt], 0, 0, 0);
        }
        f32x4 eacc = (f32x4){0.f, 0.f, 0.f, 0.f};
        {
            short8 e0 = *(const short8*)&ET[m * 64 + quad * 8];
            short8 e1 = *(const short8*)&ET[m * 64 + 32 + quad * 8];
            eacc = __builtin_amdgcn_mfma_f32_16x16x32_bf16(a0, e0, eacc, 0, 0, 0);
            eacc = __builtin_amdgcn_mfma_f32_16x16x32_bf16(a1, e1, eacc, 0, 0, 0);
        }
        int srow = bb * 64 + w * 16 + quad * 4;
#pragma unroll
        for (int nt = 0; nt < 8; ++nt) {
#pragma unroll
            for (int r = 0; r < 4; ++r) {
                int rr = srow + r;
                if (rr < NA) out[(size_t)rr * 128 + nt * 16 + m] = __float2bfloat16(acc[nt][r]);
            }
        }
        if (m < 4) {
#pragma unroll
            for (int r = 0; r < 4; ++r) {
                int rr = srow + r;
                if (rr < NA) elout[(size_t)rr * 4 + m] = eacc[r];
            }
        }
        return;
    }
    // ---- res: hbuf = x_ag @ [Wres_gt|Wres_uav] + bias + fused er GEMVs ----
    int bb = nidx - 1564;
    for (int i = t * 8; i < 256 * 64; i += 256 * 8) {
        short8 v = *(const short8*)(wrT + i);
        int n = i >> 6, k = i & 63;
        *(short8*)&Bt[n * 72 + k] = v;
    }
    bl[t] = (t < 128) ? ldf(bg, t, f32) : ldf(bu, t - 128, f32);
    __syncthreads();
    int row = bb * 64 + w * 16 + m;
    int rowc = row < NA ? row : NA - 1;
    short8 a0 = ldfrag8(xa, (size_t)rowc * 64 + quad * 8, f32);
    short8 a1 = ldfrag8(xa, (size_t)rowc * 64 + 32 + quad * 8, f32);
    f32x4 acc[16];
#pragma unroll
    for (int nt = 0; nt < 16; ++nt) acc[nt] = (f32x4){0.f, 0.f, 0.f, 0.f};
#pragma unroll
    for (int nt = 0; nt < 16; ++nt) {
        short8 b0 = *(const short8*)&Bt[(nt * 16 + m) * 72 + quad * 8];
        short8 b1 = *(const short8*)&Bt[(nt * 16 + m) * 72 + 32 + quad * 8];
        acc[nt] = __builtin_amdgcn_mfma_f32_16x16x32_bf16(a0, b0, acc[nt], 0, 0, 0);
        acc[nt] = __builtin_amdgcn_mfma_f32_16x16x32_bf16(a1, b1, acc[nt], 0, 0, 0);
    }
    f32x4 eacc = (f32x4){0.f, 0.f, 0.f, 0.f};
    {
        short8 e0 = *(const short8*)&erT[m * 64 + quad * 8];
        short8 e1 = *(const short8*)&erT[m * 64 + 32 + quad * 8];
        eacc = __builtin_amdgcn_mfma_f32_16x16x32_bf16(a0, e0, eacc, 0, 0, 0);
        eacc = __builtin_amdgcn_mfma_f32_16x16x32_bf16(a1, e1, eacc, 0, 0, 0);
    }
    int srow = bb * 64 + w * 16 + quad * 4;
#pragma unroll
    for (int nt = 0; nt < 16; ++nt) {
        int col = nt * 16 + m;
#pragma unroll
        for (int r = 0; r < 4; ++r) {
            int rr = srow + r;
            if (rr < NA)
                hbuf[(size_t)rr * 256 + col] = __float2bfloat16(acc[nt][r] + bl[col]);
        }
    }
    if (m < 8) {
        float* ero = (m < 4) ? (elbase + 200000) : (elbase + 600000);
        int mm = m & 3;
#pragma unroll
        for (int r = 0; r < 4; ++r) {
            int rr = srow + r;
            if (rr < NA) ero[(size_t)rr * 4 + mm] = eacc[r];
        }
    }
}

// scan1 v2: LDS-FREE fold (coalesced global RMW, prefix in registers) +
// last-block ticket folds tops (scan2's job).
__global__ void scan1_k(unsigned char* hist, unsigned int* row, unsigned int* tops) {
    __shared__ unsigned int sh[256];
    __shared__ int lastf;
    int b = blockIdx.x, t = threadIdx.x;
    int base = b * 1024;
    int off = base + t * 4;
    unsigned int run0 = 0u, run1 = 0u, run2 = 0u, run3 = 0u;
    if (off + 4 <= HROW) {
        for (int c = 0; c < NCH; ++c) {
            unsigned int* hp = (unsigned int*)(hist + (size_t)c * HROW + off);
            unsigned int w = *hp;
            *hp = run0 | (run1 << 8) | (run2 << 16) | (run3 << 24);
            run0 += w & 255u;
            run1 += (w >> 8) & 255u;
            run2 += (w >> 16) & 255u;
            run3 += (w >> 24) & 255u;
        }
    }
    unsigned int v[4];
    v[0] = (base + t * 4 + 0 < 100000) ? run0 : 0u;
    v[1] = (base + t * 4 + 1 < 100000) ? run1 : 0u;
    v[2] = (base + t * 4 + 2 < 100000) ? run2 : 0u;
    v[3] = (base + t * 4 + 3 < 100000) ? run3 : 0u;
    unsigned int s = v[0] + v[1] + v[2] + v[3];
    sh[t] = s;
    __syncthreads();
    for (int o = 1; o < 256; o <<= 1) {
        unsigned int x = (t >= o) ? sh[t - o] : 0u;
        __syncthreads();
        sh[t] += x;
        __syncthreads();
    }
    unsigned int run = sh[t] - s;
    for (int j = 0; j < 4; ++j) {
        if (base + t * 4 + j < 100000) row[base + t * 4 + j] = run;
        run += v[j];
    }
    if (t == 255) tops[b] = sh[255];
    // ---- last-block top-scan (replaces scan2_k) ----
    __threadfence();
    __syncthreads();
    if (t == 0) {
        unsigned int tk = atomicAdd(&tops[120], 1u);
        lastf = (tk == 97u);
    }
    __syncthreads();
    if (!lastf) return;
    unsigned int tv = (t < 98) ? __hip_atomic_load(&tops[t], __ATOMIC_RELAXED,
                                                   __HIP_MEMORY_SCOPE_AGENT)
                               : 0u;
    __syncthreads();
    sh[t] = tv;
    __syncthreads();
    for (int o = 1; o < 256; o <<= 1) {
        unsigned int x = (t >= o) ? sh[t - o] : 0u;
        __syncthreads();
        sh[t] += x;
        __syncthreads();
    }
    if (t < 98) tops[t] = sh[t] - tv;   // exclusive global base per block
    if (t == 97) row[100000] = tv;      // block-97 local total
}

// scatter v2: 4 edges/thread ILP (grid 1172 blocks).
__global__ void scatter_k(const int* sg, const int* dg, const int* su, const int* du,
                          const float* elbase, const unsigned int* row,
                          const unsigned int* tops,
                          const unsigned char* hist, const unsigned char* rank8,
                          unsigned int* recs) {
    int q = blockIdx.x * 256 + threadIdx.x;
    if (q >= 2 * NE / 4) return;
    int idx0 = q * 4;
    int g = idx0 >= NE;
    int e0 = idx0 - g * NE;
    int4 s4 = *(const int4*)((g ? su : sg) + e0);
    int4 d4 = *(const int4*)((g ? du : dg) + e0);
    uchar4 r4 = *(const uchar4*)(rank8 + (size_t)idx0);
    int c = g * 48 + e0 / CHE;
    const float4* el4 = (const float4*)(elbase + (g ? 400000 : 0));
    const float4* er4 = (const float4*)(elbase + (g ? 600000 : 200000));
    const unsigned char* ch = hist + (size_t)c * HROW + g * NA;
    int ss[4] = {s4.x, s4.y, s4.z, s4.w};
    int dd[4] = {d4.x, d4.y, d4.z, d4.w};
    unsigned int lr[4] = {r4.x, r4.y, r4.z, r4.w};
    unsigned int cb[4], ro[4], tp[4];
    float4 l[4], r[4];
#pragma unroll
    for (int k = 0; k < 4; ++k) {
        int bin = g * NA + dd[k];
        cb[k] = ch[dd[k]];
        ro[k] = row[bin];
        tp[k] = tops[bin >> 10];
        l[k] = el4[ss[k]];
        r[k] = er4[dd[k]];
    }
#pragma unroll
    for (int k = 0; k < 4; ++k) {
        unsigned int pos = ro[k] + tp[k] + cb[k] + lr[k];
        uint3 rec;
        rec.x = (unsigned int)ss[k];
        rec.y = pack_bf16x2(lrelu_exp(l[k].x + r[k].x), lrelu_exp(l[k].y + r[k].y));
        rec.z = pack_bf16x2(lrelu_exp(l[k].z + r[k].z), lrelu_exp(l[k].w + r[k].w));
        *(uint3*)(recs + (size_t)pos * 3) = rec;
    }
}

// clamped rec load: deg-0 dsts read slot 0 (always valid; weight is masked)
__device__ __forceinline__ uint3 ldrec(const unsigned int* recs, unsigned int s,
                                       unsigned int e, unsigned int slot) {
    unsigned int idx = s + slot;
    unsigned int c = (s < e) ? (idx < e ? idx : e - 1) : 0u;
    return *(const uint3*)(recs + (size_t)c * 3);
}

// 16-edge round accumulate (dot2 packed math, identical numerics to v8)
__device__ __forceinline__ void gacc16(unsigned int rbase, unsigned int e,
                                       const uint3* rr, const uint4* uu,
                                       int hsel, unsigned int shl, int eg,
                                       float& denom, float* a) {
#pragma unroll
    for (int p = 0; p < 2; ++p) {
        int j0 = 2 * p, j1 = 2 * p + 1;
        unsigned int pp0 = hsel ? rr[j0].z : rr[j0].y;
        unsigned int pp1 = hsel ? rr[j1].z : rr[j1].y;
        pp0 <<= shl;
        pp1 <<= shl;
        if (rbase + 4 * j0 + eg >= e) pp0 = 0u;
        if (rbase + 4 * j1 + eg >= e) pp1 = 0u;
        unsigned int w01 = __builtin_amdgcn_perm(pp1, pp0, 0x07060302u);
        denom = dot2bf(w01, 0x3F803F80u, denom);
        const unsigned int* u0 = (const unsigned int*)&uu[j0];
        const unsigned int* u1 = (const unsigned int*)&uu[j1];
#pragma unroll
        for (int w2 = 0; w2 < 4; ++w2) {
            unsigned int lop = __builtin_amdgcn_perm(u1[w2], u0[w2], 0x05040100u);
            unsigned int hip = __builtin_amdgcn_perm(u1[w2], u0[w2], 0x07060302u);
            a[2 * w2]     = dot2bf(lop, w01, a[2 * w2]);
            a[2 * w2 + 1] = dot2bf(hip, w01, a[2 * w2 + 1]);
        }
    }
}

// gather v11: ONE WAVE PER 4 CONSECUTIVE DSTS (25k waves, 6250 blocks).
// Per-wave fixed cost (row/tops/hbuf prologue, rec->fs chain, shfl epilogue)
// dominated v9's 50us (inner-loop cuts only moved 3-5%). CSR contiguity lets
// one wave batch 4 dsts: ranges loaded once, hbuf RMW reads batched, and the
// pipeline runs ACROSS dsts — dst i+1's fs issues from already-arrived recs
// during dst i's compute; dst i+2's recs issue alongside. rec->fs latency
// paid ~once per wave instead of once per dst. Deg>16 tails (~10%) serial.
__global__ void gather_k(const unsigned int* row, const unsigned int* tops,
                         const unsigned int* recs,
                         const bf16* fs, bf16* hbuf) {
    int wv = (blockIdx.x * 256 + threadIdx.x) >> 6;
    int lane = threadIdx.x & 63;
    if (wv >= 25000) return;
    int g = wv / 12500;
    int d0 = (wv - g * 12500) * 4;
    int bin0 = g * NA + d0;
    int eg = lane >> 4;
    int cl = lane & 15;
    int hsel = cl >> 3;
    unsigned int shl = ((cl >> 2) & 1) ? 0u : 16u;
    unsigned int st[5];
#pragma unroll
    for (int i = 0; i < 5; ++i) st[i] = row[bin0 + i] + tops[(bin0 + i) >> 10];
    const uint4* fs4 = (const uint4*)(fs + (size_t)g * NA * 128);
    uint4 rv[4];
    if (lane < 16) {
#pragma unroll
        for (int i = 0; i < 4; ++i)
            rv[i] = *((uint4*)(hbuf + (size_t)(d0 + i) * 256 + g * 128) + cl);
    }

    uint3 rA[4], rB[4], rC[4];
    uint4 uA[4], uB[4];
#pragma unroll
    for (int j = 0; j < 4; ++j) rA[j] = ldrec(recs, st[0], st[1], 4 * j + eg);
#pragma unroll
    for (int j = 0; j < 4; ++j) uA[j] = fs4[(size_t)rA[j].x * 16 + cl];
#pragma unroll
    for (int j = 0; j < 4; ++j) rB[j] = ldrec(recs, st[1], st[2], 4 * j + eg);

#pragma unroll
    for (int i = 0; i < 4; ++i) {
        unsigned int s = st[i], e = st[i + 1];
        if (i < 3) {
#pragma unroll
            for (int j = 0; j < 4; ++j) uB[j] = fs4[(size_t)rB[j].x * 16 + cl];
        }
        if (i < 2) {
#pragma unroll
            for (int j = 0; j < 4; ++j) rC[j] = ldrec(recs, st[i + 2], st[i + 3], 4 * j + eg);
        }
        float denom = 0.f;
        float a[8];
#pragma unroll
        for (int k = 0; k < 8; ++k) a[k] = 0.f;
        if (s < e) {
            gacc16(s, e, rA, uA, hsel, shl, eg, denom, a);
            for (unsigned int ii = s + 16; ii < e; ii += 16) {  // deg>16 tail
                uint3 rT[4];
                uint4 uT[4];
#pragma unroll
                for (int j = 0; j < 4; ++j) {
                    unsigned int idx = ii + 4 * j + eg;
                    rT[j] = *(const uint3*)(recs + (size_t)(idx < e ? idx : e - 1) * 3);
                }
#pragma unroll
                for (int j = 0; j < 4; ++j) uT[j] = fs4[(size_t)rT[j].x * 16 + cl];
                gacc16(ii, e, rT, uT, hsel, shl, eg, denom, a);
            }
        }
#pragma unroll
        for (int k = 0; k < 8; ++k) {
            a[k] += __shfl_xor(a[k], 16, 64);
            a[k] += __shfl_xor(a[k], 32, 64);
        }
        denom += __shfl_xor(denom, 16, 64);
        denom += __shfl_xor(denom, 32, 64);
        if (lane < 16) {
            float inv = (e > s) ? 1.f / denom : 0.f;
            uint4* hp = (uint4*)(hbuf + (size_t)(d0 + i) * 256 + g * 128) + cl;
            float v0 = a[0] * inv + lo_f(rv[i].x);
            float v1 = a[1] * inv + hi_f(rv[i].x);
            float v2 = a[2] * inv + lo_f(rv[i].y);
            float v3 = a[3] * inv + hi_f(rv[i].y);
            float v4 = a[4] * inv + lo_f(rv[i].z);
            float v5 = a[5] * inv + hi_f(rv[i].z);
            float v6 = a[6] * inv + lo_f(rv[i].w);
            float v7 = a[7] * inv + hi_f(rv[i].w);
            v0 = v0 > 0.f ? v0 : 0.f;
            v1 = v1 > 0.f ? v1 : 0.f;
            v2 = v2 > 0.f ? v2 : 0.f;
            v3 = v3 > 0.f ? v3 : 0.f;
            v4 = v4 > 0.f ? v4 : 0.f;
            v5 = v5 > 0.f ? v5 : 0.f;
            v6 = v6 > 0.f ? v6 : 0.f;
            v7 = v7 > 0.f ? v7 : 0.f;
            uint4 o;
            o.x = pack_bf16x2(v0, v1);
            o.y = pack_bf16x2(v2, v3);
            o.z = pack_bf16x2(v4, v5);
            o.w = pack_bf16x2(v6, v7);
            *hp = o;
        }
#pragma unroll
        for (int j = 0; j < 4; ++j) { rA[j] = rB[j]; uA[j] = uB[j]; rB[j] = rC[j]; }
    }
}

// MFMA final: out = relu(hbuf @ W_f + b_f). LDS-staged per 64-k chunk.
__global__ void final_k(const bf16* hbuf, const unsigned short* wfT,
                        const void* bfp, void* outp, const int* flag) {
    int f32 = *flag;
    int b = blockIdx.x;
    __shared__ unsigned short Bt[128 * 72];  // 18 KB
    __shared__ float bl[128];
    int t = threadIdx.x;
    if (t < 128) bl[t] = ldf(bfp, t, f32);
    int lane = t & 63, w = t >> 6;
    int m = lane & 15, quad = lane >> 4;
    int row = b * 64 + w * 16 + m;
    int rowc = row < NA ? row : NA - 1;
    f32x4 acc[8];
#pragma unroll
    for (int nt = 0; nt < 8; ++nt) acc[nt] = (f32x4){0.f, 0.f, 0.f, 0.f};
    for (int kc = 0; kc < 4; ++kc) {
        __syncthreads();
        for (int i = t * 8; i < 128 * 64; i += 256 * 8) {
            int n = i >> 6, k = i & 63;
            short8 v = *(const short8*)(wfT + (size_t)n * 256 + kc * 64 + k);
            *(short8*)&Bt[n * 72 + k] = v;
        }
        __syncthreads();
        short8 a0 = *(const short8*)((const unsigned short*)hbuf +
                                     (size_t)rowc * 256 + kc * 64 + quad * 8);
        short8 a1 = *(const short8*)((const unsigned short*)hbuf +
                                     (size_t)rowc * 256 + kc * 64 + 32 + quad * 8);
#pragma unroll
        for (int nt = 0; nt < 8; ++nt) {
            short8 b0 = *(const short8*)&Bt[(nt * 16 + m) * 72 + quad * 8];
            short8 b1 = *(const short8*)&Bt[(nt * 16 + m) * 72 + 32 + quad * 8];
            acc[nt] = __builtin_amdgcn_mfma_f32_16x16x32_bf16(a0, b0, acc[nt], 0, 0, 0);
            acc[nt] = __builtin_amdgcn_mfma_f32_16x16x32_bf16(a1, b1, acc[nt], 0, 0, 0);
        }
    }
    int srow = b * 64 + w * 16 + quad * 4;
#pragma unroll
    for (int nt = 0; nt < 8; ++nt) {
        int col = nt * 16 + m;
        float bv = bl[col];
#pragma unroll
        for (int r = 0; r < 4; ++r) {
            int rr = srow + r;
            if (rr < NA) {
                float v = acc[nt][r] + bv;
                v = v > 0.f ? v : 0.f;
                if (f32) ((float*)outp)[(size_t)rr * 128 + col] = v;
                else ((bf16*)outp)[(size_t)rr * 128 + col] = __float2bfloat16(v);
            }
        }
    }
}

extern "C" void kernel_launch(void* const* d_in, const int* in_sizes, int n_in,
                              void* d_out, int out_size, void* d_ws, size_t ws_size,
                              hipStream_t stream) {
    const void* x_gt     = d_in[0];
    const void* x_uav    = d_in[1];
    const void* x_ag     = d_in[2];
    const int*  src_gt   = (const int*)d_in[3];
    const int*  dst_gt   = (const int*)d_in[4];
    const int*  src_uav  = (const int*)d_in[5];
    const int*  dst_uav  = (const int*)d_in[6];
    const void* Wsrc_gt  = d_in[7];
    const void* Wdst_gt  = d_in[8];
    const void* al_gt    = d_in[9];
    const void* ar_gt    = d_in[10];
    const void* Wres_gt  = d_in[11];
    const void* b_gt     = d_in[12];
    const void* Wsrc_uav = d_in[13];
    const void* Wdst_uav = d_in[14];
    const void* al_uav   = d_in[15];
    const void* ar_uav   = d_in[16];
    const void* Wres_uav = d_in[17];
    const void* b_uav    = d_in[18];
    const void* W_f      = d_in[19];
    const void* b_f      = d_in[20];

    char* wsb = (char*)d_ws;
    bf16* hbuf = (bf16*)(wsb + HBUF_B);
    bf16* fs = (bf16*)(wsb + FS_B);
    float* el = (float*)(wsb + EL_B);
    unsigned int* recs = (unsigned int*)(wsb + RECS_B);
    unsigned char* hist = (unsigned char*)(wsb + HIST_B);
    unsigned int* row = (unsigned int*)(wsb + ROW_B);
    unsigned int* tops = (unsigned int*)(wsb + TOPS_B);
    int* flag = (int*)(wsb + FLAG_B);
    unsigned short* wsT_gt = (unsigned short*)(wsb + WST_GT_B);
    unsigned short* wsT_uav = (unsigned short*)(wsb + WST_UAV_B);
    unsigned short* wrT = (unsigned short*)(wsb + WRT_B);
    unsigned short* wfT = (unsigned short*)(wsb + WFT_B);
    unsigned short* elT_gt = (unsigned short*)(wsb + ELT_GT_B);
    unsigned short* elT_uav = (unsigned short*)(wsb + ELT_UAV_B);
    unsigned short* erT = (unsigned short*)(wsb + ERT_B);
    unsigned char* rank8 = (unsigned char*)(wsb + RANK8_B);

    if (ws_size < (size_t)WS_BYTES) {
        hipMemsetAsync(d_out, 0x42, (size_t)out_size * 2, stream);
        return;
    }

    long sent = (long)out_size / 2 - 1;

    HeteroVisionConv_29703993819529_kernel<<<21, 256, 0, stream>>>(
        x_gt, Wsrc_gt, al_gt, Wdst_gt, ar_gt, Wsrc_uav, al_uav, Wdst_uav, ar_uav,
        Wres_gt, Wres_uav, W_f,
        wsT_gt, wsT_uav, wrT, wfT, elT_gt, elT_uav, erT, tops,
        flag, (unsigned int*)d_out, sent);
    fused_k<<<NCH + 2346, 256, 0, stream>>>(dst_gt, dst_uav, hist, rank8,
                                            x_gt, x_uav, x_ag,
                                            wsT_gt, wsT_uav, elT_gt, elT_uav,
                                            wrT, erT, b_gt, b_uav,
                                            el, fs, hbuf, flag);
    scan1_k<<<98, 256, 0, stream>>>(hist, row, tops);
    scatter_k<<<1172, 256, 0, stream>>>(src_gt, dst_gt, src_uav, dst_uav,
                                        el, row, tops, hist, rank8, recs);
    gather_k<<<6250, 256, 0, stream>>>(row, tops, recs, fs, hbuf);
    final_k<<<782, 256, 0, stream>>>(hbuf, wfT, b_f, d_out, flag);
}

// Round 14
// 274.857 us; speedup vs baseline: 1.0358x; 1.0358x over previous
//
#include <hip/hip_runtime.h>
#include <hip/hip_bf16.h>

using bf16 = __hip_bfloat16;

#define NA 50000
#define NE 600000

// 96 chunks x 12500 edges; hist rows padded to 100032 bins (3 passes x 33344)
#define NCH 96
#define CHE 12500
#define HROW 100032
#define PBINS 33344

typedef __attribute__((ext_vector_type(8))) short short8;
typedef __attribute__((ext_vector_type(4))) float f32x4;

// ---- ws layout (BYTE offsets). Total ~80.1 MB (< proven-safe 81.6 MB) ----
#define HBUF_B   0u            // bf16 50000x256                      25.6 MB
#define FS_B     25600000u     // bf16 2 x 50000x128                  25.6 MB
#define EL_B     51200000u     // f32 4 x 200,000: el_gt, er_gt, el_uav, er_uav
#define RECS_B   54400000u     // 12B recs x 1.2M {src,ee01,ee23}     14.4 MB
#define HIST_B   68800000u     // u8 [96][100032] counts -> prefixes   9.6 MB
#define ROW_B    78403072u     // u32 100001 LOCAL row offsets (block-local)
#define TOPS_B   78803076u     // u32 128: [0..97] block bases, [120] ticket
#define FLAG_B   78803588u     // int dtype flag
#define WST_GT_B 78803600u     // bf16 128x64 transposed W_src_gt     16 KB
#define WST_UAV_B 78819984u    // bf16 128x64                         16 KB
#define WRT_B    78836368u     // bf16 256x64 transposed [Wres_gt|Wres_uav]
#define WFT_B    78869136u     // bf16 128x256 transposed W_f         64 KB
#define ELT_GT_B 78934672u     // bf16 16x64 el-weights gt (rows 4-15 zero)
#define ELT_UAV_B 78936720u    // bf16 16x64
#define ERT_B    78938768u     // bf16 16x64 er gt rows0-3, uav rows4-7, 8-15 zero
#define RANK8_B  78940816u     // u8 1.2M per-edge local rank (captured in fused_k)
#define WS_BYTES 80140816u

__device__ __forceinline__ float b2f(bf16 v) { return __bfloat162float(v); }

__device__ __forceinline__ float ldf(const void* p, size_t i, int f32) {
    return f32 ? ((const float*)p)[i] : b2f(((const bf16*)p)[i]);
}

__device__ __forceinline__ unsigned short f2bs(float v) {
    bf16 t = __float2bfloat16(v);
    return *(unsigned short*)&t;
}

__device__ __forceinline__ float lrelu_exp(float v) {
    v = v > 0.f ? v : 0.2f * v;
    return __expf(v);
}

__device__ __forceinline__ unsigned int pack_bf16x2(float a, float b) {
    return (unsigned int)f2bs(a) | ((unsigned int)f2bs(b) << 16);
}

__device__ __forceinline__ float lo_f(unsigned int u) { return __uint_as_float(u << 16); }
__device__ __forceinline__ float hi_f(unsigned int u) { return __uint_as_float(u & 0xffff0000u); }

// v_dot2_f32_bf16 (VOP3P, CDNA3+): d = a.bf16[0]*b.bf16[0] + a.bf16[1]*b.bf16[1] + c
__device__ __forceinline__ float dot2bf(unsigned int a, unsigned int b, float c) {
    float d;
    asm("v_dot2_f32_bf16 %0, %1, %2, %3" : "=v"(d) : "v"(a), "v"(b), "v"(c));
    return d;
}

__device__ __forceinline__ short8 ldfrag8(const void* p, size_t off, int f32) {
    if (!f32) return *(const short8*)((const unsigned short*)p + off);
    union { short8 s; unsigned int u[4]; } r;
    const float* fp = (const float*)p + off;
#pragma unroll
    for (int j = 0; j < 4; ++j) r.u[j] = pack_bf16x2(fp[2 * j], fp[2 * j + 1]);
    return r.s;
}

__device__ int probe_f32(const void* x0) {
    __shared__ int cnt;
    if (threadIdx.x == 0) cnt = 0;
    __syncthreads();
    const bf16* p = (const bf16*)x0;
    int bad = 0;
    for (int i = threadIdx.x; i < 1024; i += 256) {
        float av = fabsf(b2f(p[i]));
        if (!(av <= 1e6f)) bad++;
    }
    if (bad) atomicAdd(&cnt, bad);
    __syncthreads();
    return cnt > 8;
}

// prep (weights only): 21 blocks convert weight tables + set flag/sentinel.
// Transposes READ COALESCED, scatter-write the transposed table.
__global__ void HeteroVisionConv_29703993819529_kernel(
    const void* x0,
    const void* Wsg, const void* alg, const void* Wdg, const void* arg_,
    const void* Wsu, const void* alu, const void* Wdu, const void* aru,
    const void* Wrg, const void* Wru, const void* Wf,
    unsigned short* wsT_gt, unsigned short* wsT_uav, unsigned short* wrT,
    unsigned short* wfT, unsigned short* elT_gt, unsigned short* elT_uav,
    unsigned short* erT, unsigned int* tops,
    int* flag, unsigned int* outp, long sent) {
    int b = blockIdx.x, t = threadIdx.x;
    int f32 = probe_f32(x0);
    if (b == 20) {
        if (t == 0) { flag[0] = f32; tops[120] = 0u; outp[sent] = 0x447A447Au; }
        return;
    }
    if (b < 8) {               // WfT: source rows k in [b*32, b*32+32); Wf is 256x128
        for (int i = t; i < 32 * 128; i += 256) {
            int k = b * 32 + (i >> 7), n = i & 127;
            wfT[n * 256 + k] = f2bs(ldf(Wf, (size_t)k * 128 + n, f32));
        }
    } else if (b < 12) {       // WrT: source rows k in [(b-8)*16, +16); Wr* are 64x128
        for (int i = t; i < 16 * 256; i += 256) {
            int k = (b - 8) * 16 + (i >> 8), n = i & 255;
            float v = (n < 128) ? ldf(Wrg, (size_t)k * 128 + n, f32)
                                : ldf(Wru, (size_t)k * 128 + (n - 128), f32);
            wrT[n * 64 + k] = f2bs(v);
        }
    } else if (b < 14) {       // WsT_gt: source rows k in [(b-12)*32, +32); Wsg 64x128
        for (int i = t; i < 32 * 128; i += 256) {
            int k = (b - 12) * 32 + (i >> 7), n = i & 127;
            wsT_gt[n * 64 + k] = f2bs(ldf(Wsg, (size_t)k * 128 + n, f32));
        }
    } else if (b < 16) {       // WsT_uav halves
        for (int i = t; i < 32 * 128; i += 256) {
            int k = (b - 14) * 32 + (i >> 7), n = i & 127;
            wsT_uav[n * 64 + k] = f2bs(ldf(Wsu, (size_t)k * 128 + n, f32));
        }
    } else {                   // fold attn weights, m = b-16
        int m = b - 16;
        const void* Wm = (m == 0) ? Wsg : (m == 1) ? Wdg : (m == 2) ? Wsu : Wdu;
        const void* Am = (m == 0) ? alg : (m == 1) ? arg_ : (m == 2) ? alu : aru;
        int k = t >> 2, h = t & 3;
        float a = 0.f;
        for (int d = 0; d < 32; ++d)
            a += ldf(Wm, (size_t)k * 128 + h * 32 + d, f32) *
                 ldf(Am, (size_t)h * 32 + d, f32);
        unsigned short v = f2bs(a);
        if (m == 0) {
            elT_gt[h * 64 + k] = v;
            for (int i = t; i < 12 * 64; i += 256) elT_gt[(4 + (i >> 6)) * 64 + (i & 63)] = 0;
        } else if (m == 2) {
            elT_uav[h * 64 + k] = v;
            for (int i = t; i < 12 * 64; i += 256) elT_uav[(4 + (i >> 6)) * 64 + (i & 63)] = 0;
        } else if (m == 1) {
            erT[h * 64 + k] = v;
        } else {
            erT[(4 + h) * 64 + k] = v;
            for (int i = t; i < 8 * 64; i += 256) erT[(8 + (i >> 6)) * 64 + (i & 63)] = 0;
        }
    }
}

// fused_k: ATOMIC-FREE histogram (96 per-chunk blocks, LDS u8 counts,
// 3 bin-passes of 33344 bins reusing the Bt LDS) + node_fs/res MFMA blocks.
// hist[c][bin] = count of chunk-c edges in bin; LDS atomicAdd return value
// is the edge's local rank -> rank8[]. Grid: 96 + 1564 + 782 = 2442 blocks.
__global__ void fused_k(const int* dg, const int* du,
                        unsigned char* hist, unsigned char* rank8,
                        const void* xg, const void* xu, const void* xa,
                        const unsigned short* wsT_gt, const unsigned short* wsT_uav,
                        const unsigned short* elT_gt, const unsigned short* elT_uav,
                        const unsigned short* wrT, const unsigned short* erT,
                        const void* bg, const void* bu,
                        float* elbase, bf16* fs, bf16* hbuf, const int* flag) {
    __shared__ unsigned short Bt[256 * 72];  // 36 KB (hist reuses as u32[8336])
    __shared__ float bl[256];
    int b = blockIdx.x, t = threadIdx.x;

    if (b < NCH) {
        // ---- per-chunk histogram + rank capture, LDS-only counting ----
        int c = b;
        int g = c >= 48;
        int eoff = (c - g * 48) * CHE;
        const int* dp = (g ? du : dg) + eoff;
        unsigned char* rk = rank8 + (size_t)g * NE + eoff;
        unsigned int* h32 = (unsigned int*)Bt;
        for (int p = 0; p < 3; ++p) {
            int binLo = p * PBINS;
            unsigned int* out = (unsigned int*)(hist + (size_t)c * HROW + binLo);
            bool live = (binLo + PBINS > g * NA) && (binLo < g * NA + NA);
            if (!live) {  // chunk's bins don't intersect this pass: write zeros
                for (int i = t; i < PBINS / 4; i += 256) out[i] = 0u;
                continue;
            }
            for (int i = t; i < PBINS / 4; i += 256) h32[i] = 0u;
            __syncthreads();
            for (int i = t; i < CHE / 4; i += 256) {
                int4 d4 = *(const int4*)(dp + i * 4);
                int dd[4] = {d4.x, d4.y, d4.z, d4.w};
#pragma unroll
                for (int k = 0; k < 4; ++k) {
                    int rel = g * NA + dd[k] - binLo;
                    if (rel >= 0 && rel < PBINS) {
                        unsigned int sh8 = 8u * (rel & 3);
                        unsigned int old = atomicAdd(&h32[rel >> 2], 1u << sh8);
                        rk[i * 4 + k] = (unsigned char)((old >> sh8) & 255u);
                    }
                }
            }
            __syncthreads();
            for (int i = t; i < PBINS / 4; i += 256) out[i] = h32[i];
            __syncthreads();
        }
        return;
    }
    int nidx = b - NCH;
    int f32 = *flag;
    int lane = t & 63, w = t >> 6;
    int m = lane & 15, quad = lane >> 4;

    if (nidx < 1564) {
        // ---- node_fs: fs = x_src @ W_src + fused el GEMV ----
        int g = nidx / 782, bb = nidx % 782;
        const void* A = g ? xu : xg;
        const unsigned short* WT = g ? wsT_uav : wsT_gt;
        const unsigned short* ET = g ? elT_uav : elT_gt;
        float* elout = elbase + (g ? 400000 : 0);
        bf16* out = fs + (size_t)g * NA * 128;
        for (int i = t * 8; i < 128 * 64; i += 256 * 8) {
            short8 v = *(const short8*)(WT + i);
            int n = i >> 6, k = i & 63;
            *(short8*)&Bt[n * 72 + k] = v;
        }
        __syncthreads();
        int row = bb * 64 + w * 16 + m;
        int rowc = row < NA ? row : NA - 1;
        short8 a0 = ldfrag8(A, (size_t)rowc * 64 + quad * 8, f32);
        short8 a1 = ldfrag8(A, (size_t)rowc * 64 + 32 + quad * 8, f32);
        f32x4 acc[8];
#pragma unroll
        for (int nt = 0; nt < 8; ++nt) acc[nt] = (f32x4){0.f, 0.f, 0.f, 0.f};
#pragma unroll
        for (int nt = 0; nt < 8; ++nt) {
            short8 b0 = *(const short8*)&Bt[(nt * 16 + m) * 72 + quad * 8];
            short8 b1 = *(const short8*)&Bt[(nt * 16 + m) * 72 + 32 + quad * 8];
            acc[nt] = __builtin_amdgcn_mfma_f32_16x16x32_bf16(a0, b0, acc[nt], 0, 0, 0);
            acc[nt] = __builtin_amdgcn_mfma_f32_16x16x32_bf16(a1, b1, acc[nt], 0, 0, 0);
        }
        f32x4 eacc = (f32x4){0.f, 0.f, 0.f, 0.f};
        {
            short8 e0 = *(const short8*)&ET[m * 64 + quad * 8];
            short8 e1 = *(const short8*)&ET[m * 64 + 32 + quad * 8];
            eacc = __builtin_amdgcn_mfma_f32_16x16x32_bf16(a0, e0, eacc, 0, 0, 0);
            eacc = __builtin_amdgcn_mfma_f32_16x16x32_bf16(a1, e1, eacc, 0, 0, 0);
        }
        int srow = bb * 64 + w * 16 + quad * 4;
#pragma unroll
        for (int nt = 0; nt < 8; ++nt) {
#pragma unroll
            for (int r = 0; r < 4; ++r) {
                int rr = srow + r;
                if (rr < NA) out[(size_t)rr * 128 + nt * 16 + m] = __float2bfloat16(acc[nt][r]);
            }
        }
        if (m < 4) {
#pragma unroll
            for (int r = 0; r < 4; ++r) {
                int rr = srow + r;
                if (rr < NA) elout[(size_t)rr * 4 + m] = eacc[r];
            }
        }
        return;
    }
    // ---- res: hbuf = x_ag @ [Wres_gt|Wres_uav] + bias + fused er GEMVs ----
    int bb = nidx - 1564;
    for (int i = t * 8; i < 256 * 64; i += 256 * 8) {
        short8 v = *(const short8*)(wrT + i);
        int n = i >> 6, k = i & 63;
        *(short8*)&Bt[n * 72 + k] = v;
    }
    bl[t] = (t < 128) ? ldf(bg, t, f32) : ldf(bu, t - 128, f32);
    __syncthreads();
    int row = bb * 64 + w * 16 + m;
    int rowc = row < NA ? row : NA - 1;
    short8 a0 = ldfrag8(xa, (size_t)rowc * 64 + quad * 8, f32);
    short8 a1 = ldfrag8(xa, (size_t)rowc * 64 + 32 + quad * 8, f32);
    f32x4 acc[16];
#pragma unroll
    for (int nt = 0; nt < 16; ++nt) acc[nt] = (f32x4){0.f, 0.f, 0.f, 0.f};
#pragma unroll
    for (int nt = 0; nt < 16; ++nt) {
        short8 b0 = *(const short8*)&Bt[(nt * 16 + m) * 72 + quad * 8];
        short8 b1 = *(const short8*)&Bt[(nt * 16 + m) * 72 + 32 + quad * 8];
        acc[nt] = __builtin_amdgcn_mfma_f32_16x16x32_bf16(a0, b0, acc[nt], 0, 0, 0);
        acc[nt] = __builtin_amdgcn_mfma_f32_16x16x32_bf16(a1, b1, acc[nt], 0, 0, 0);
    }
    f32x4 eacc = (f32x4){0.f, 0.f, 0.f, 0.f};
    {
        short8 e0 = *(const short8*)&erT[m * 64 + quad * 8];
        short8 e1 = *(const short8*)&erT[m * 64 + 32 + quad * 8];
        eacc = __builtin_amdgcn_mfma_f32_16x16x32_bf16(a0, e0, eacc, 0, 0, 0);
        eacc = __builtin_amdgcn_mfma_f32_16x16x32_bf16(a1, e1, eacc, 0, 0, 0);
    }
    int srow = bb * 64 + w * 16 + quad * 4;
#pragma unroll
    for (int nt = 0; nt < 16; ++nt) {
        int col = nt * 16 + m;
#pragma unroll
        for (int r = 0; r < 4; ++r) {
            int rr = srow + r;
            if (rr < NA)
                hbuf[(size_t)rr * 256 + col] = __float2bfloat16(acc[nt][r] + bl[col]);
        }
    }
    if (m < 8) {
        float* ero = (m < 4) ? (elbase + 200000) : (elbase + 600000);
        int mm = m & 3;
#pragma unroll
        for (int r = 0; r < 4; ++r) {
            int rr = srow + r;
            if (rr < NA) ero[(size_t)rr * 4 + mm] = eacc[r];
        }
    }
}

// scan1 v2: LDS-FREE fold (coalesced global RMW, prefix in registers) +
// last-block ticket folds tops (scan2's job).
__global__ void scan1_k(unsigned char* hist, unsigned int* row, unsigned int* tops) {
    __shared__ unsigned int sh[256];
    __shared__ int lastf;
    int b = blockIdx.x, t = threadIdx.x;
    int base = b * 1024;
    int off = base + t * 4;
    unsigned int run0 = 0u, run1 = 0u, run2 = 0u, run3 = 0u;
    if (off + 4 <= HROW) {
        for (int c = 0; c < NCH; ++c) {
            unsigned int* hp = (unsigned int*)(hist + (size_t)c * HROW + off);
            unsigned int w = *hp;
            *hp = run0 | (run1 << 8) | (run2 << 16) | (run3 << 24);
            run0 += w & 255u;
            run1 += (w >> 8) & 255u;
            run2 += (w >> 16) & 255u;
            run3 += (w >> 24) & 255u;
        }
    }
    unsigned int v[4];
    v[0] = (base + t * 4 + 0 < 100000) ? run0 : 0u;
    v[1] = (base + t * 4 + 1 < 100000) ? run1 : 0u;
    v[2] = (base + t * 4 + 2 < 100000) ? run2 : 0u;
    v[3] = (base + t * 4 + 3 < 100000) ? run3 : 0u;
    unsigned int s = v[0] + v[1] + v[2] + v[3];
    sh[t] = s;
    __syncthreads();
    for (int o = 1; o < 256; o <<= 1) {
        unsigned int x = (t >= o) ? sh[t - o] : 0u;
        __syncthreads();
        sh[t] += x;
        __syncthreads();
    }
    unsigned int run = sh[t] - s;
    for (int j = 0; j < 4; ++j) {
        if (base + t * 4 + j < 100000) row[base + t * 4 + j] = run;
        run += v[j];
    }
    if (t == 255) tops[b] = sh[255];
    // ---- last-block top-scan (replaces scan2_k) ----
    __threadfence();
    __syncthreads();
    if (t == 0) {
        unsigned int tk = atomicAdd(&tops[120], 1u);
        lastf = (tk == 97u);
    }
    __syncthreads();
    if (!lastf) return;
    unsigned int tv = (t < 98) ? __hip_atomic_load(&tops[t], __ATOMIC_RELAXED,
                                                   __HIP_MEMORY_SCOPE_AGENT)
                               : 0u;
    __syncthreads();
    sh[t] = tv;
    __syncthreads();
    for (int o = 1; o < 256; o <<= 1) {
        unsigned int x = (t >= o) ? sh[t - o] : 0u;
        __syncthreads();
        sh[t] += x;
        __syncthreads();
    }
    if (t < 98) tops[t] = sh[t] - tv;   // exclusive global base per block
    if (t == 97) row[100000] = tv;      // block-97 local total
}

// scatter v1 (restored — measured best vs v2 by A/B: 275.0 vs 280.4):
// pure streaming, ATOMIC-FREE, no replay.
// pos = row[bin] + tops[bin>>10] + hist[c][bin] + rank8[e].
__global__ void scatter_k(const int* sg, const int* dg, const int* su, const int* du,
                          const float* elbase, const unsigned int* row,
                          const unsigned int* tops,
                          const unsigned char* hist, const unsigned char* rank8,
                          unsigned int* recs) {
    int idx = blockIdx.x * 256 + threadIdx.x;
    if (idx >= 2 * NE) return;
    int g = idx >= NE;
    int e = idx - g * NE;
    int s = (g ? su : sg)[e];
    int d = (g ? du : dg)[e];
    int c = g * 48 + e / CHE;
    int bin = g * NA + d;
    const float4* el4 = (const float4*)(elbase + (g ? 400000 : 0));
    const float4* er4 = (const float4*)(elbase + (g ? 600000 : 200000));
    unsigned int lr = rank8[idx];
    unsigned int cb = hist[(size_t)c * HROW + bin];
    unsigned int pos = row[bin] + tops[bin >> 10] + cb + lr;
    float4 l = el4[s], r = er4[d];
    uint3 rec;
    rec.x = (unsigned int)s;
    rec.y = pack_bf16x2(lrelu_exp(l.x + r.x), lrelu_exp(l.y + r.y));
    rec.z = pack_bf16x2(lrelu_exp(l.z + r.z), lrelu_exp(l.w + r.w));
    *(uint3*)(recs + (size_t)pos * 3) = rec;
}

// gather v9 (FROZEN at its measured floor 49.4us — four structural attacks
// all lost to this version): one wave per (dst,g); 16 lanes/edge, 8 cols via
// one uint4 fs load; 4 edge-groups x 4-deep ILP = 16 edges/round; 2-stage
// pipeline (next round's fs issued from already-arrived recs, round+2 recs
// prefetched); dot2 packed math; early hbuf RMW read.
__global__ void gather_k(const unsigned int* row, const unsigned int* tops,
                         const unsigned int* recs,
                         const bf16* fs, bf16* hbuf) {
    int wid = (blockIdx.x * 256 + threadIdx.x) >> 6;
    int lane = threadIdx.x & 63;
    if (wid >= 2 * NA) return;
    int g = wid / NA, d = wid - g * NA;
    int bin = g * NA + d;
    int eg = lane >> 4;        // edge group 0..3 within the batch
    int cl = lane & 15;        // col-lane: covers cols cl*8 .. cl*8+7
    int hsel = cl >> 3;        // head>=2 -> rec.z
    unsigned int shl = ((cl >> 2) & 1) ? 0u : 16u;  // even head: lo half -> shift to hi
    unsigned int start = row[bin] + tops[bin >> 10];
    unsigned int end   = row[bin + 1] + tops[(bin + 1) >> 10];
    const uint4* fs4 = (const uint4*)(fs + (size_t)g * NA * 128);
    uint4* hp = (uint4*)(hbuf + (size_t)d * 256 + g * 128) + cl;
    uint4 rv;
    if (lane < 16) rv = *hp;   // early RMW read: hides under the whole loop

    float denom = 0.f;
    float a[8];
#pragma unroll
    for (int k = 0; k < 8; ++k) a[k] = 0.f;

    if (start < end) {
        uint3 rr[4], rn[4];
        uint4 uu[4];
#pragma unroll
        for (int j = 0; j < 4; ++j) {       // round-0 recs
            unsigned int idx = start + 4 * j + eg;
            rr[j] = *(const uint3*)(recs + (size_t)(idx < end ? idx : end - 1) * 3);
        }
#pragma unroll
        for (int j = 0; j < 4; ++j)         // round-0 fs
            uu[j] = fs4[(size_t)rr[j].x * 16 + cl];
#pragma unroll
        for (int j = 0; j < 4; ++j) {       // round-1 recs
            unsigned int idx = start + 16 + 4 * j + eg;
            rn[j] = *(const uint3*)(recs + (size_t)(idx < end ? idx : end - 1) * 3);
        }
        for (unsigned int i = start; i < end; i += 16) {
            uint4 un[4];
            uint3 rnn[4];
#pragma unroll
            for (int j = 0; j < 4; ++j)     // NEXT round's fs (rn already here)
                un[j] = fs4[(size_t)rn[j].x * 16 + cl];
#pragma unroll
            for (int j = 0; j < 4; ++j) {   // round+2 recs
                unsigned int idx = i + 32 + 4 * j + eg;
                rnn[j] = *(const uint3*)(recs + (size_t)(idx < end ? idx : end - 1) * 3);
            }
#pragma unroll
            for (int p = 0; p < 2; ++p) {   // compute on rr/uu (fetched last round)
                int j0 = 2 * p, j1 = 2 * p + 1;
                unsigned int pp0 = hsel ? rr[j0].z : rr[j0].y;
                unsigned int pp1 = hsel ? rr[j1].z : rr[j1].y;
                pp0 <<= shl;                 // target bf16 now in hi16
                pp1 <<= shl;
                if (i + 4 * j0 + eg >= end) pp0 = 0u;
                if (i + 4 * j1 + eg >= end) pp1 = 0u;
                unsigned int w01 = __builtin_amdgcn_perm(pp1, pp0, 0x07060302u);
                denom = dot2bf(w01, 0x3F803F80u, denom);  // + e0 + e1
                const unsigned int* u0 = (const unsigned int*)&uu[j0];
                const unsigned int* u1 = (const unsigned int*)&uu[j1];
#pragma unroll
                for (int w2 = 0; w2 < 4; ++w2) {
                    unsigned int lop = __builtin_amdgcn_perm(u1[w2], u0[w2], 0x05040100u);
                    unsigned int hip = __builtin_amdgcn_perm(u1[w2], u0[w2], 0x07060302u);
                    a[2 * w2]     = dot2bf(lop, w01, a[2 * w2]);
                    a[2 * w2 + 1] = dot2bf(hip, w01, a[2 * w2 + 1]);
                }
            }
#pragma unroll
            for (int j = 0; j < 4; ++j) { rr[j] = rn[j]; rn[j] = rnn[j]; uu[j] = un[j]; }
        }
    }
#pragma unroll
    for (int k = 0; k < 8; ++k) {
        a[k] += __shfl_xor(a[k], 16, 64);
        a[k] += __shfl_xor(a[k], 32, 64);
    }
    denom += __shfl_xor(denom, 16, 64);
    denom += __shfl_xor(denom, 32, 64);
    if (lane < 16) {
        float inv = (end > start) ? 1.f / denom : 0.f;
        float v0 = a[0] * inv + lo_f(rv.x);
        float v1 = a[1] * inv + hi_f(rv.x);
        float v2 = a[2] * inv + lo_f(rv.y);
        float v3 = a[3] * inv + hi_f(rv.y);
        float v4 = a[4] * inv + lo_f(rv.z);
        float v5 = a[5] * inv + hi_f(rv.z);
        float v6 = a[6] * inv + lo_f(rv.w);
        float v7 = a[7] * inv + hi_f(rv.w);
        v0 = v0 > 0.f ? v0 : 0.f;
        v1 = v1 > 0.f ? v1 : 0.f;
        v2 = v2 > 0.f ? v2 : 0.f;
        v3 = v3 > 0.f ? v3 : 0.f;
        v4 = v4 > 0.f ? v4 : 0.f;
        v5 = v5 > 0.f ? v5 : 0.f;
        v6 = v6 > 0.f ? v6 : 0.f;
        v7 = v7 > 0.f ? v7 : 0.f;
        uint4 o;
        o.x = pack_bf16x2(v0, v1);
        o.y = pack_bf16x2(v2, v3);
        o.z = pack_bf16x2(v4, v5);
        o.w = pack_bf16x2(v6, v7);
        *hp = o;
    }
}

// MFMA final: out = relu(hbuf @ W_f + b_f). LDS-staged per 64-k chunk.
__global__ void final_k(const bf16* hbuf, const unsigned short* wfT,
                        const void* bfp, void* outp, const int* flag) {
    int f32 = *flag;
    int b = blockIdx.x;
    __shared__ unsigned short Bt[128 * 72];  // 18 KB
    __shared__ float bl[128];
    int t = threadIdx.x;
    if (t < 128) bl[t] = ldf(bfp, t, f32);
    int lane = t & 63, w = t >> 6;
    int m = lane & 15, quad = lane >> 4;
    int row = b * 64 + w * 16 + m;
    int rowc = row < NA ? row : NA - 1;
    f32x4 acc[8];
#pragma unroll
    for (int nt = 0; nt < 8; ++nt) acc[nt] = (f32x4){0.f, 0.f, 0.f, 0.f};
    for (int kc = 0; kc < 4; ++kc) {
        __syncthreads();
        for (int i = t * 8; i < 128 * 64; i += 256 * 8) {
            int n = i >> 6, k = i & 63;
            short8 v = *(const short8*)(wfT + (size_t)n * 256 + kc * 64 + k);
            *(short8*)&Bt[n * 72 + k] = v;
        }
        __syncthreads();
        short8 a0 = *(const short8*)((const unsigned short*)hbuf +
                                     (size_t)rowc * 256 + kc * 64 + quad * 8);
        short8 a1 = *(const short8*)((const unsigned short*)hbuf +
                                     (size_t)rowc * 256 + kc * 64 + 32 + quad * 8);
#pragma unroll
        for (int nt = 0; nt < 8; ++nt) {
            short8 b0 = *(const short8*)&Bt[(nt * 16 + m) * 72 + quad * 8];
            short8 b1 = *(const short8*)&Bt[(nt * 16 + m) * 72 + 32 + quad * 8];
            acc[nt] = __builtin_amdgcn_mfma_f32_16x16x32_bf16(a0, b0, acc[nt], 0, 0, 0);
            acc[nt] = __builtin_amdgcn_mfma_f32_16x16x32_bf16(a1, b1, acc[nt], 0, 0, 0);
        }
    }
    int srow = b * 64 + w * 16 + quad * 4;
#pragma unroll
    for (int nt = 0; nt < 8; ++nt) {
        int col = nt * 16 + m;
        float bv = bl[col];
#pragma unroll
        for (int r = 0; r < 4; ++r) {
            int rr = srow + r;
            if (rr < NA) {
                float v = acc[nt][r] + bv;
                v = v > 0.f ? v : 0.f;
                if (f32) ((float*)outp)[(size_t)rr * 128 + col] = v;
                else ((bf16*)outp)[(size_t)rr * 128 + col] = __float2bfloat16(v);
            }
        }
    }
}

extern "C" void kernel_launch(void* const* d_in, const int* in_sizes, int n_in,
                              void* d_out, int out_size, void* d_ws, size_t ws_size,
                              hipStream_t stream) {
    const void* x_gt     = d_in[0];
    const void* x_uav    = d_in[1];
    const void* x_ag     = d_in[2];
    const int*  src_gt   = (const int*)d_in[3];
    const int*  dst_gt   = (const int*)d_in[4];
    const int*  src_uav  = (const int*)d_in[5];
    const int*  dst_uav  = (const int*)d_in[6];
    const void* Wsrc_gt  = d_in[7];
    const void* Wdst_gt  = d_in[8];
    const void* al_gt    = d_in[9];
    const void* ar_gt    = d_in[10];
    const void* Wres_gt  = d_in[11];
    const void* b_gt     = d_in[12];
    const void* Wsrc_uav = d_in[13];
    const void* Wdst_uav = d_in[14];
    const void* al_uav   = d_in[15];
    const void* ar_uav   = d_in[16];
    const void* Wres_uav = d_in[17];
    const void* b_uav    = d_in[18];
    const void* W_f      = d_in[19];
    const void* b_f      = d_in[20];

    char* wsb = (char*)d_ws;
    bf16* hbuf = (bf16*)(wsb + HBUF_B);
    bf16* fs = (bf16*)(wsb + FS_B);
    float* el = (float*)(wsb + EL_B);
    unsigned int* recs = (unsigned int*)(wsb + RECS_B);
    unsigned char* hist = (unsigned char*)(wsb + HIST_B);
    unsigned int* row = (unsigned int*)(wsb + ROW_B);
    unsigned int* tops = (unsigned int*)(wsb + TOPS_B);
    int* flag = (int*)(wsb + FLAG_B);
    unsigned short* wsT_gt = (unsigned short*)(wsb + WST_GT_B);
    unsigned short* wsT_uav = (unsigned short*)(wsb + WST_UAV_B);
    unsigned short* wrT = (unsigned short*)(wsb + WRT_B);
    unsigned short* wfT = (unsigned short*)(wsb + WFT_B);
    unsigned short* elT_gt = (unsigned short*)(wsb + ELT_GT_B);
    unsigned short* elT_uav = (unsigned short*)(wsb + ELT_UAV_B);
    unsigned short* erT = (unsigned short*)(wsb + ERT_B);
    unsigned char* rank8 = (unsigned char*)(wsb + RANK8_B);

    if (ws_size < (size_t)WS_BYTES) {
        hipMemsetAsync(d_out, 0x42, (size_t)out_size * 2, stream);
        return;
    }

    long sent = (long)out_size / 2 - 1;

    HeteroVisionConv_29703993819529_kernel<<<21, 256, 0, stream>>>(
        x_gt, Wsrc_gt, al_gt, Wdst_gt, ar_gt, Wsrc_uav, al_uav, Wdst_uav, ar_uav,
        Wres_gt, Wres_uav, W_f,
        wsT_gt, wsT_uav, wrT, wfT, elT_gt, elT_uav, erT, tops,
        flag, (unsigned int*)d_out, sent);
    fused_k<<<NCH + 2346, 256, 0, stream>>>(dst_gt, dst_uav, hist, rank8,
                                            x_gt, x_uav, x_ag,
                                            wsT_gt, wsT_uav, elT_gt, elT_uav,
                                            wrT, erT, b_gt, b_uav,
                                            el, fs, hbuf, flag);
    scan1_k<<<98, 256, 0, stream>>>(hist, row, tops);
    scatter_k<<<4688, 256, 0, stream>>>(src_gt, dst_gt, src_uav, dst_uav,
                                        el, row, tops, hist, rank8, recs);
    gather_k<<<25000, 256, 0, stream>>>(row, tops, recs, fs, hbuf);
    final_k<<<782, 256, 0, stream>>>(hbuf, wfT, b_f, d_out, flag);
}